// Round 19
// baseline (2999.739 us; speedup 1.0000x reference)
//
#include <hip/hip_runtime.h>

#define Hh 64
#define Tt 2048
#define Bb 256
#define NL 3
#define CH 16
#define NCH 128            // Tt/CH
#define NR (NCH + NL - 1)  // 130 rounds

typedef _Float16 h2 __attribute__((ext_vector_type(2)));
__device__ __forceinline__ h2 uh2(unsigned u){union{unsigned u;h2 h;}d;d.u=u;return d.h;}
#define FDOT2(a,b,c) __builtin_amdgcn_fdot2((a),(b),(c),false)

__device__ __forceinline__ float fast_sigmoid(float x){ return 1.0f/(1.0f+__expf(-x)); }
__device__ __forceinline__ float fast_tanh(float x){ float e=__expf(2.0f*x); return 1.0f-2.0f/(e+1.0f); }

__global__ void conv_w(const float* __restrict__ src, _Float16* __restrict__ dst, int n){
    int i = blockIdx.x*256 + threadIdx.x;
    if (i < n) dst[i] = (_Float16)src[i];
}

__global__ __launch_bounds__(256)
void prep_x(const float* __restrict__ x, _Float16* __restrict__ xh){
    __shared__ float tile[64][65];
    const int b = blockIdx.x, tc = blockIdx.y;
    const int tt = threadIdx.x & 63, hq = threadIdx.x >> 6;
    const long xb = (long)b * Hh * Tt;
#pragma unroll
    for (int k=0;k<16;++k){ int h = hq*16+k; tile[h][tt] = x[xb + (long)h*Tt + tc*64 + tt]; }
    __syncthreads();
    _Float16* dst = xh + ((long)b*Tt + tc*64 + tt)*Hh + hq*16;
#pragma unroll
    for (int k=0;k<16;++k) dst[k] = (_Float16)tile[hq*16+k][tt];
}

// ---- main: 12 waves, 4/layer, layers pipelined with CHUNK skew (16 steps) ----
// R11-R18 law: phase ~= weight-bytes / pipe-BW, streams don't overlap. Fix the
// BYTES: only Whh (73.7KB/phase, all layers) is recurrent. Wih's contribution
// gx = Wih*input + bih is computed per-CHUNK at round boundaries (layer l's
// chunk-c input = layer l-1's chunk-c h, complete at skew 16; layer 0 from x).
// In-loop stream: Whh only, conflict-free slot layout (R17-proven:
// consecutive lanes <-> consecutive 16B). Boundary GEMM: 768 thr x 4 rows x
// (3 tiles) fdot2, Wih re-read from L2 once per 16 steps (amortized 1.5KB/step).
__global__
__attribute__((amdgpu_flat_work_group_size(768, 768)))
void gru_pipe(const _Float16* __restrict__ xh, float* __restrict__ out,
              const _Float16* __restrict__ wih16, const _Float16* __restrict__ whh16,
              const float* __restrict__ bih, const float* __restrict__ bhh)
{
    const int b   = blockIdx.x;
    const int tid = threadIdx.x;
    const int w   = tid >> 6;        // 0..11
    const int l   = w >> 2;          // layer
    const int s   = (w >> 1) & 1;    // role: 0 -> r-gate + n(hh-side); 1 -> z-gate + finish
    const int uh  = w & 1;           // unit half
    const int ln  = tid & 63;
    const int kh  = ln >> 5;         // k half
    const int jj  = ln & 31;
    const int j   = uh * 32 + jj;    // hidden unit
    const int gid = (l*2 + uh)*64 + ln;   // 0..383 within each s-class

    __shared__ __align__(16) uint4 wr4[4*384], wz4[4*384], wn4[4*384]; // Whh r/z/n: 73,728 B
    __shared__ float gx[NL][CH][192];                  // 36,864 B: per-chunk Wih*input+bih
    __shared__ _Float16 htile[2][CH][Hh];              // 4,096 B: h chunks (l0->l1, l1->l2)
    __shared__ __align__(16) _Float16 xstage[CH][Hh];  // 2,048 B: x chunk for l0 gemm
    __shared__ __align__(16) _Float16 hbuf[NL][2][Hh]; // own-layer h, dbuf by parity
    __shared__ float ubuf[NL][Hh];
    __shared__ float obuf[2][32][33];

    // ---- one-time Whh stage (each lane parks the rows it will consume) ----
    if (s == 0) {
        const uint4* sr = (const uint4*)(whh16 + ((long)l*192 +       j)*64 + kh*32);
        const uint4* sn = (const uint4*)(whh16 + ((long)l*192 + 128 + j)*64 + kh*32);
#pragma unroll
        for (int q = 0; q < 4; ++q) { wr4[q*384 + gid] = sr[q]; wn4[q*384 + gid] = sn[q]; }
    } else {
        const uint4* sz = (const uint4*)(whh16 + ((long)l*192 +  64 + j)*64 + kh*32);
#pragma unroll
        for (int q = 0; q < 4; ++q) { wz4[q*384 + gid] = sz[q]; }
    }
    float bR = 0.0f, bN = 0.0f, bZ = 0.0f;
    if (s == 0) { bR = bhh[l*192 + j]; bN = bhh[l*192 + 128 + j]; }
    else        { bZ = bhh[l*192 + 64 + j]; }

    if (tid < NL*2*Hh) ((_Float16*)hbuf)[tid] = (_Float16)0.0f;
    float hprev = 0.0f;

    const long ib  = (long)b * Hh * Tt;   // [B,H,T] out base
    const long ibh = (long)b * Tt * Hh;   // [B,T,H] xh base
    const int  g2  = tid % 192, rq = tid / 192;   // gemm mapping

    for (int round = 0; round < NR; ++round) {
        // ---- boundary: stage x chunk; compute gx tiles for this round ----
        if (round < NCH && tid < 128)
            ((uint4*)xstage)[tid] = ((const uint4*)(xh + ibh + (long)round*CH*Hh))[tid];
        __syncthreads();   // xstage ready; htiles from previous round complete
#pragma unroll
        for (int lt = 0; lt < NL; ++lt) {
            const int c = round - lt;
            if (c < 0 || c >= NCH) continue;
            const uint4* wrow = (const uint4*)(wih16 + ((long)lt*192 + g2)*64);
            const uint4 W0=wrow[0],W1=wrow[1],W2=wrow[2],W3=wrow[3],
                        W4=wrow[4],W5=wrow[5],W6=wrow[6],W7=wrow[7];
            const _Float16* inp = (lt == 0) ? &xstage[0][0] : &htile[lt-1][0][0];
            const float bv = bih[lt*192 + g2];
#pragma unroll
            for (int i = 0; i < 4; ++i) {
                const int row = rq*4 + i;
                const h2* xr = (const h2*)(inp + row*Hh);
                float a = bv;
#define GQA(Wq, o) { a=FDOT2(uh2((Wq).x),xr[(o)+0],a); a=FDOT2(uh2((Wq).y),xr[(o)+1],a); \
                     a=FDOT2(uh2((Wq).z),xr[(o)+2],a); a=FDOT2(uh2((Wq).w),xr[(o)+3],a); }
                GQA(W0,0) GQA(W1,4) GQA(W2,8) GQA(W3,12)
                GQA(W4,16) GQA(W5,20) GQA(W6,24) GQA(W7,28)
#undef GQA
                gx[lt][row][g2] = a;
            }
        }
        __syncthreads();   // gx tiles ready

        // ---- 16 lockstep scan steps ----
        const int cl  = round - l;
        const bool act = (cl >= 0) && (cl < NCH);
        for (int tm = 0; tm < CH; ++tm) {
            const int p  = round*CH + tm;
            const int rd = p & 1;
            const int t  = cl*CH + tm;

            unsigned goff = gid * 16u;
            asm volatile("" : "+v"(goff));   // ds_reads stay in-loop (R16-18 proven)

            float accB = 0.0f, accC = 0.0f, g1 = 0.0f;
            if (act) {
                const uint4* hs4 = (const uint4*)hbuf[l][rd] + kh*4;
                const uint4 hq0 = hs4[0], hq1 = hs4[1], hq2 = hs4[2], hq3 = hs4[3];
#define DOTG(dst, reg) { \
    const uint4 q0 = *(const uint4*)((const char*)(reg) + goff); \
    const uint4 q1 = *(const uint4*)((const char*)(reg) + goff + 6144); \
    const uint4 q2 = *(const uint4*)((const char*)(reg) + goff + 12288); \
    const uint4 q3 = *(const uint4*)((const char*)(reg) + goff + 18432); \
    dst=FDOT2(uh2(q0.x),uh2(hq0.x),dst); dst=FDOT2(uh2(q0.y),uh2(hq0.y),dst); \
    dst=FDOT2(uh2(q0.z),uh2(hq0.z),dst); dst=FDOT2(uh2(q0.w),uh2(hq0.w),dst); \
    dst=FDOT2(uh2(q1.x),uh2(hq1.x),dst); dst=FDOT2(uh2(q1.y),uh2(hq1.y),dst); \
    dst=FDOT2(uh2(q1.z),uh2(hq1.z),dst); dst=FDOT2(uh2(q1.w),uh2(hq1.w),dst); \
    dst=FDOT2(uh2(q2.x),uh2(hq2.x),dst); dst=FDOT2(uh2(q2.y),uh2(hq2.y),dst); \
    dst=FDOT2(uh2(q2.z),uh2(hq2.z),dst); dst=FDOT2(uh2(q2.w),uh2(hq2.w),dst); \
    dst=FDOT2(uh2(q3.x),uh2(hq3.x),dst); dst=FDOT2(uh2(q3.y),uh2(hq3.y),dst); \
    dst=FDOT2(uh2(q3.z),uh2(hq3.z),dst); dst=FDOT2(uh2(q3.w),uh2(hq3.w),dst); }
                if (s == 0) { DOTG(accB, wr4) DOTG(accC, wn4) }
                else       { DOTG(accB, wz4) }
#undef DOTG
                accB += __shfl_xor(accB, 32);
                if (s == 0) {
                    accC += __shfl_xor(accC, 32);
                    const float rg = fast_sigmoid(gx[l][tm][j] + accB + bR);
                    if (kh == 0) ubuf[l][j] = rg * (accC + bN);  // r*(Whh_n.h + bhn)
                } else {
                    g1 = fast_sigmoid(gx[l][tm][64 + j] + accB + bZ);  // z
                }
            }
            __syncthreads();   // B1: u visible

            if (act && s == 1) {
                const float n = fast_tanh(gx[l][tm][128 + j] + ubuf[l][j]);
                const float hnew = fmaf(g1, hprev - n, n);   // (1-z)*n + z*h
                hprev = hnew;
                if (kh == 0) {
                    hbuf[l][rd ^ 1][j] = (_Float16)hnew;
                    if (l < 2) htile[l][tm][j] = (_Float16)hnew;
                    else       obuf[uh][jj][t & 31] = hnew;
                }
            }
            __syncthreads();   // B2: h published

            if ((w >> 1) == 5 && act && (t & 31) == 31) {
                const float* srow = obuf[uh][jj] + kh*16;
                float4* dst = (float4*)(out + ib + (long)j*Tt + (t - 31) + kh*16);
                dst[0] = make_float4(srow[0],  srow[1],  srow[2],  srow[3]);
                dst[1] = make_float4(srow[4],  srow[5],  srow[6],  srow[7]);
                dst[2] = make_float4(srow[8],  srow[9],  srow[10], srow[11]);
                dst[3] = make_float4(srow[12], srow[13], srow[14], srow[15]);
            }
        }
    }
}

extern "C" void kernel_launch(void* const* d_in, const int* in_sizes, int n_in,
                              void* d_out, int out_size, void* d_ws, size_t ws_size,
                              hipStream_t stream) {
    const float* x   = (const float*)d_in[0];   // [B, H, T]
    const float* Wih = (const float*)d_in[1];   // [3, 192, 64]
    const float* Whh = (const float*)d_in[2];   // [3, 192, 64]
    const float* bih = (const float*)d_in[3];   // [3, 192]
    const float* bhh = (const float*)d_in[4];   // [3, 192]
    float* out = (float*)d_out;                 // [B, H, T]

    _Float16* xh    = (_Float16*)d_ws;                               // 67,108,864 B
    _Float16* wih16 = (_Float16*)((char*)d_ws + 67108864);
    _Float16* whh16 = (_Float16*)((char*)d_ws + 67108864 + 73728);
    const int nW = NL * 192 * 64;  // 36864

    conv_w<<<(nW + 255) / 256, 256, 0, stream>>>(Wih, wih16, nW);
    conv_w<<<(nW + 255) / 256, 256, 0, stream>>>(Whh, whh16, nW);
    prep_x<<<dim3(Bb, Tt / 64), 256, 0, stream>>>(x, xh);
    gru_pipe<<<Bb, 768, 0, stream>>>(xh, out, wih16, whh16, bih, bhh);
}

// Round 20
// 2191.580 us; speedup vs baseline: 1.3688x; 1.3688x over previous
//
#include <hip/hip_runtime.h>

#define Hh 64
#define Tt 2048
#define Bb 256
#define NL 3
#define CH 16
#define NCH 128            // Tt/CH
#define NR (NCH + NL - 1)  // 130 rounds

typedef _Float16 h2 __attribute__((ext_vector_type(2)));
__device__ __forceinline__ h2 uh2(unsigned u){union{unsigned u;h2 h;}d;d.u=u;return d.h;}
#define FDOT2(a,b,c) __builtin_amdgcn_fdot2((a),(b),(c),false)

__device__ __forceinline__ float fast_sigmoid(float x){ return 1.0f/(1.0f+__expf(-x)); }
__device__ __forceinline__ float fast_tanh(float x){ float e=__expf(2.0f*x); return 1.0f-2.0f/(e+1.0f); }

__global__ void conv_w(const float* __restrict__ src, _Float16* __restrict__ dst, int n){
    int i = blockIdx.x*256 + threadIdx.x;
    if (i < n) dst[i] = (_Float16)src[i];
}

__global__ __launch_bounds__(256)
void prep_x(const float* __restrict__ x, _Float16* __restrict__ xh){
    __shared__ float tile[64][65];
    const int b = blockIdx.x, tc = blockIdx.y;
    const int tt = threadIdx.x & 63, hq = threadIdx.x >> 6;
    const long xb = (long)b * Hh * Tt;
#pragma unroll
    for (int k=0;k<16;++k){ int h = hq*16+k; tile[h][tt] = x[xb + (long)h*Tt + tc*64 + tt]; }
    __syncthreads();
    _Float16* dst = xh + ((long)b*Tt + tc*64 + tt)*Hh + hq*16;
#pragma unroll
    for (int k=0;k<16;++k) dst[k] = (_Float16)tile[hq*16+k][tt];
}

// ---- main: 3 waves/block, ONE wave per layer, chunk-skew 16 ----
// R11-R19 lesson: 2-barrier lockstep serializes LDS/VMEM/VALU (phase = SUM of
// streams + latencies). Here the 16-step scan has ZERO block barriers: each
// wave is self-synchronous (own h row in LDS; wave-wide ds_write + explicit
// lgkmcnt(0) + sched_barrier makes next step's broadcast read safe). Cross-
// wave handoff (h chunk -> next layer) only at round boundaries: 1 barrier
// per 16 steps. Weight streams split across pipes so they overlap:
//   Whh r,z: LDS, conflict-free slot layout (16 b128/step/wave)
//   Whh n:   L2 global (8 b128/step/wave, hidden under r/z FDOT2s)
//   Wih:     per-chunk boundary GEMM, row-outer (8 quads live -> no remat)
__global__ __launch_bounds__(192, 1)
void gru_pipe(const _Float16* __restrict__ xh, float* __restrict__ out,
              const _Float16* __restrict__ wih16, const _Float16* __restrict__ whh16,
              const float* __restrict__ bih, const float* __restrict__ bhh)
{
    const int b   = blockIdx.x;
    const int tid = threadIdx.x;
    const int l   = tid >> 6;     // wave = layer 0..2
    const int j   = tid & 63;     // unit

    __shared__ __align__(16) uint4   wrz[16 * 192];        // 49,152 B: Whh r,z
    __shared__ float    gx[NL][CH][192];                    // 36,864 B
    __shared__ __align__(16) _Float16 htile[2][2][CH][Hh];  // 8,192 B [producer][buf]
    __shared__ __align__(16) _Float16 xstage[CH][Hh];       // 2,048 B
    __shared__ __align__(16) _Float16 hwork[NL][Hh];        //   384 B
    __shared__ float    obuf[Hh][33];                       // 8,448 B

    // stage Whh r,z rows: slot layout [q*192 + tid] -> consecutive lanes,
    // consecutive 16B (R17-proven conflict-free)
    {
        const uint4* wr = (const uint4*)(whh16 + ((long)l*192 +      j)*64);
        const uint4* wz = (const uint4*)(whh16 + ((long)l*192 + 64 + j)*64);
#pragma unroll
        for (int q = 0; q < 8; ++q) {
            wrz[q*192 + tid]       = wr[q];
            wrz[(8+q)*192 + tid]   = wz[q];
        }
    }
    const uint4* wng = (const uint4*)(whh16 + ((long)l*192 + 128 + j)*64);  // n row, L2
    const float bR = bhh[l*192 + j];
    const float bZ = bhh[l*192 + 64 + j];
    const float bN = bhh[l*192 + 128 + j];
    const uint4* wi0 = (const uint4*)(wih16 + ((long)l*192 +       j)*64);
    const uint4* wi1 = (const uint4*)(wih16 + ((long)l*192 +  64 + j)*64);
    const uint4* wi2 = (const uint4*)(wih16 + ((long)l*192 + 128 + j)*64);
    const float bi0 = bih[l*192 + j], bi1 = bih[l*192 + 64 + j], bi2 = bih[l*192 + 128 + j];

    hwork[l][j] = (_Float16)0.0f;
    float hprev = 0.0f;

    const long ib  = (long)b * Hh * Tt;
    const long ibh = (long)b * Tt * Hh;

    for (int round = 0; round < NR; ++round) {
        __syncthreads();   // the ONLY barrier: htile chunks from round-1 now visible
        const int c = round - l;
        const bool act = (c >= 0) && (c < NCH);

        // ---- boundary: x chunk load (wave 0) + gx GEMM (each wave, own layer) ----
        if (l == 0 && round < NCH) {
            const uint4* src = (const uint4*)(xh + ibh + (long)round*CH*Hh);
            ((uint4*)xstage)[j]      = src[j];
            ((uint4*)xstage)[64 + j] = src[64 + j];
        }
        if (act) {
            const _Float16* inp = (l == 0) ? &xstage[0][0]
                                           : &htile[l-1][(round-1) & 1][0][0];
#define GQ(Wq, Xq) { a=FDOT2(uh2((Wq).x),uh2((Xq).x),a); a=FDOT2(uh2((Wq).y),uh2((Xq).y),a); \
                     a=FDOT2(uh2((Wq).z),uh2((Xq).z),a); a=FDOT2(uh2((Wq).w),uh2((Xq).w),a); }
#pragma unroll
            for (int r3 = 0; r3 < 3; ++r3) {
                const uint4* wp = (r3 == 0) ? wi0 : (r3 == 1) ? wi1 : wi2;
                const float bb  = (r3 == 0) ? bi0 : (r3 == 1) ? bi1 : bi2;
                const int  col  = r3*64 + j;
                const uint4 W0=wp[0],W1=wp[1],W2=wp[2],W3=wp[3],
                            W4=wp[4],W5=wp[5],W6=wp[6],W7=wp[7];
#pragma unroll
                for (int t = 0; t < CH; ++t) {
                    const uint4* xr = (const uint4*)(inp + t*Hh);
                    const uint4 X0=xr[0],X1=xr[1],X2=xr[2],X3=xr[3],
                                X4=xr[4],X5=xr[5],X6=xr[6],X7=xr[7];
                    float a = bb;
                    GQ(W0,X0) GQ(W1,X1) GQ(W2,X2) GQ(W3,X3)
                    GQ(W4,X4) GQ(W5,X5) GQ(W6,X6) GQ(W7,X7)
                    gx[l][t][col] = a;
                }
            }
#undef GQ
        }

        // ---- 16 wave-synchronous scan steps (no block barrier) ----
        if (act) {
            for (int tm = 0; tm < CH; ++tm) {
                const int t = c*CH + tm;

                // opaque offsets: keep LDS/global weight reads inside the loop
                unsigned off = tid * 16u, goff = 0;
                asm volatile("" : "+v"(off), "+v"(goff));
                const char*  wbase = (const char*)wrz + off;
                const uint4* wn    = (const uint4*)((const char*)wng + goff);

                // issue n-row global loads first (latency hides under r/z dots)
                const uint4 n0=wn[0],n1=wn[1],n2=wn[2],n3=wn[3],
                            n4=wn[4],n5=wn[5],n6=wn[6],n7=wn[7];
                const uint4* hq = (const uint4*)hwork[l];   // uniform broadcast
                const uint4 h0=hq[0],h1=hq[1],h2_=hq[2],h3=hq[3],
                            h4=hq[4],h5=hq[5],h6=hq[6],h7=hq[7];

                const float gxr = gx[l][tm][j];
                const float gxz = gx[l][tm][64 + j];
                const float gxn = gx[l][tm][128 + j];

                float aR = bR, aZ = bZ, aN = bN;
#define SQ(q, Nq, Hq) { \
    const uint4 wr_ = *(const uint4*)(wbase + (q)*3072); \
    const uint4 wz_ = *(const uint4*)(wbase + (8+(q))*3072); \
    aR=FDOT2(uh2(wr_.x),uh2((Hq).x),aR); aR=FDOT2(uh2(wr_.y),uh2((Hq).y),aR); \
    aR=FDOT2(uh2(wr_.z),uh2((Hq).z),aR); aR=FDOT2(uh2(wr_.w),uh2((Hq).w),aR); \
    aZ=FDOT2(uh2(wz_.x),uh2((Hq).x),aZ); aZ=FDOT2(uh2(wz_.y),uh2((Hq).y),aZ); \
    aZ=FDOT2(uh2(wz_.z),uh2((Hq).z),aZ); aZ=FDOT2(uh2(wz_.w),uh2((Hq).w),aZ); \
    aN=FDOT2(uh2((Nq).x),uh2((Hq).x),aN); aN=FDOT2(uh2((Nq).y),uh2((Hq).y),aN); \
    aN=FDOT2(uh2((Nq).z),uh2((Hq).z),aN); aN=FDOT2(uh2((Nq).w),uh2((Hq).w),aN); }
                SQ(0,n0,h0) SQ(1,n1,h1) SQ(2,n2,h2_) SQ(3,n3,h3)
                SQ(4,n4,h4) SQ(5,n5,h5) SQ(6,n6,h6) SQ(7,n7,h7)
#undef SQ
                const float r = fast_sigmoid(gxr + aR);
                const float z = fast_sigmoid(gxz + aZ);
                const float n = fast_tanh(fmaf(r, aN, gxn));
                const float hnew = fmaf(z, hprev - n, n);   // (1-z)*n + z*h
                hprev = hnew;

                hwork[l][j] = (_Float16)hnew;
                if (l < 2) htile[l][round & 1][tm][j] = (_Float16)hnew;
                else {
                    obuf[j][t & 31] = hnew;
                    if ((t & 31) == 31) {
                        const float* srow = obuf[j];
                        float4* dst = (float4*)(out + ib + (long)j*Tt + (t - 31));
#pragma unroll
                        for (int k2 = 0; k2 < 8; ++k2)
                            dst[k2] = make_float4(srow[4*k2], srow[4*k2+1],
                                                  srow[4*k2+2], srow[4*k2+3]);
                    }
                }
                // wave-synchronous fence: h write visible before next step's read
                asm volatile("s_waitcnt lgkmcnt(0)" ::: "memory");
                __builtin_amdgcn_sched_barrier(0);
            }
        }
    }
}

extern "C" void kernel_launch(void* const* d_in, const int* in_sizes, int n_in,
                              void* d_out, int out_size, void* d_ws, size_t ws_size,
                              hipStream_t stream) {
    const float* x   = (const float*)d_in[0];   // [B, H, T]
    const float* Wih = (const float*)d_in[1];   // [3, 192, 64]
    const float* Whh = (const float*)d_in[2];   // [3, 192, 64]
    const float* bih = (const float*)d_in[3];   // [3, 192]
    const float* bhh = (const float*)d_in[4];   // [3, 192]
    float* out = (float*)d_out;                 // [B, H, T]

    _Float16* xh    = (_Float16*)d_ws;                               // 67,108,864 B
    _Float16* wih16 = (_Float16*)((char*)d_ws + 67108864);
    _Float16* whh16 = (_Float16*)((char*)d_ws + 67108864 + 73728);
    const int nW = NL * 192 * 64;  // 36864

    conv_w<<<(nW + 255) / 256, 256, 0, stream>>>(Wih, wih16, nW);
    conv_w<<<(nW + 255) / 256, 256, 0, stream>>>(Whh, whh16, nW);
    prep_x<<<dim3(Bb, Tt / 64), 256, 0, stream>>>(x, xh);
    gru_pipe<<<Bb, 192, 0, stream>>>(xh, out, wih16, whh16, bih, bhh);
}